// Round 13
// baseline (83.034 us; speedup 1.0000x reference)
//
#include <hip/hip_runtime.h>
#include <hip/hip_bf16.h>
#include <math.h>

#define N_ROWS 8192
#define M_ROWS 4096
#define DDIM   512
#define SDIM   16

#define BM 128
#define BN 128
#define NKB (DDIM / 32)   // 16 k-blocks of 32

typedef __attribute__((ext_vector_type(8))) __bf16 bf16x8;
typedef __attribute__((ext_vector_type(4))) float f32x4;

__device__ __forceinline__ unsigned short f2bf_rne(float f) {
  unsigned u = __float_as_uint(f);
  u += 0x7fffu + ((u >> 16) & 1u);
  return (unsigned short)(u >> 16);
}

// Blocked fragment layout: matrix [R rows][512 k] stored as blocks
// (rb = row/16, kb = k/32), block = 1024 B contiguous at
// base = (rb*16 + kb)*512 ushorts. Inner granule for (row,k):
// lane l = (k%32)/8*16 + row%16 at byte l*16 — exactly the
// mfma_f32_16x16x32_bf16 A/B operand mapping (row=l&15, k=(l>>4)*8+j).
// A wave's fragment load = 64 lanes x 16B contiguous = 1 KiB coalesced.

// One row per WAVE (4 rows per 256-thread block). Reads coalesced f32;
// writes 16B granules scattered within the row's 16 KiB of blocks.
__global__ __launch_bounds__(256) void prep_kernel(
    const float* __restrict__ x, const float* __restrict__ y,
    const float* __restrict__ samp_x, const float* __restrict__ samp_y,
    const float* __restrict__ scale,
    ushort* __restrict__ xb, ushort* __restrict__ yb,
    float* __restrict__ sqx, float* __restrict__ sqy,
    float* __restrict__ ssx, float* __restrict__ ssy)
{
  const int tid  = threadIdx.x;
  const int lane = tid & 63;
  const int row  = blockIdx.x * 4 + (tid >> 6);

  const float* src; const float* samp; ushort* dstm; float* sqo; float* sso;
  int r;
  if (row < N_ROWS) {
    r = row;
    src = x + (size_t)r * DDIM; samp = samp_x + (size_t)r * SDIM;
    dstm = xb; sqo = sqx + r; sso = ssx + r;
  } else {
    r = row - N_ROWS;
    src = y + (size_t)r * DDIM; samp = samp_y + (size_t)r * SDIM;
    dstm = yb; sqo = sqy + r; sso = ssy + r;
  }

  // lane holds k = lane*8 .. lane*8+7
  const float4 v0 = ((const float4*)src)[lane * 2];
  const float4 v1 = ((const float4*)src)[lane * 2 + 1];
  uint4 pk;
  pk.x = (unsigned)f2bf_rne(v0.x) | ((unsigned)f2bf_rne(v0.y) << 16);
  pk.y = (unsigned)f2bf_rne(v0.z) | ((unsigned)f2bf_rne(v0.w) << 16);
  pk.z = (unsigned)f2bf_rne(v1.x) | ((unsigned)f2bf_rne(v1.y) << 16);
  pk.w = (unsigned)f2bf_rne(v1.z) | ((unsigned)f2bf_rne(v1.w) << 16);
  // blocked-layout address: rb=r>>4, kb=lane>>2, kgrp=lane&3, row15=r&15
  const size_t off = ((size_t)(r >> 4) * 16 + (lane >> 2)) * 512
                   + ((size_t)((lane & 3) * 16 + (r & 15))) * 8;
  *(uint4*)(dstm + off) = pk;

  float ss = v0.x * v0.x + v0.y * v0.y + v0.z * v0.z + v0.w * v0.w
           + v1.x * v1.x + v1.y * v1.y + v1.z * v1.z + v1.w * v1.w;
  #pragma unroll
  for (int m = 32; m >= 1; m >>= 1) ss += __shfl_xor(ss, m, 64);

  float p = (lane < SDIM) ? samp[lane] * scale[lane] : 0.f;
  #pragma unroll
  for (int m = 8; m >= 1; m >>= 1) p += __shfl_xor(p, m, 64);

  if (lane == 0) {
    *sqo = ss;
    float sp = (p > 15.f) ? p : log1pf(expf(p));   // softplus
    sp = fminf(fmaxf(sp, 1e-10f), 10000.f);
    *sso = sqrtf(sp);
  }
}

// LDS-FREE GEMM: each wave owns a 64x64 output tile (4x4 16x16 frags) and
// loads its A/B fragments DIRECTLY from the blocked global layout — every
// fragment load is 1 KiB wave-contiguous (global_load_dwordx4), L2-resident
// via the chunked XCD mapping. No LDS, no barriers, no waitcnt discipline:
// the compiler pipelines loads across the fully-unrolled 16 kb steps, and
// waves are fully independent (pure TLP).
// Chunked XCD mapping (R6-proven): XCD k owns bx in [8k,8k+8) for all by.
__global__ __launch_bounds__(256, 3) void cauchy_gemm(
    const ushort* __restrict__ xb, const ushort* __restrict__ yb,
    const float* __restrict__ sqx, const float* __restrict__ sqy,
    const float* __restrict__ ssx, const float* __restrict__ ssy,
    const float* __restrict__ cutoff, const float* __restrict__ phi,
    float* __restrict__ out)
{
  const int tid  = threadIdx.x;
  const int lane = tid & 63;
  const int w    = tid >> 6;
  const int wr = w >> 1, wc = w & 1;
  const int l15 = lane & 15, l16 = lane >> 4;

  // chunked XCD swizzle (R6): xcd = bid&7, local = bid>>3.
  const int bid   = blockIdx.x;
  const int xcd   = bid & 7;
  const int local = bid >> 3;
  const int wk    = local & 31;
  const int bx = xcd * 8 + (wk & 7);           // 64 row-blocks; bx in [8k,8k+8)
  const int by = (local >> 5) * 4 + (wk >> 3); // 32 col-blocks

  // fragment base pointers: block (rb, kb) at (rb*16+kb)*512 ushorts; +lane*8
  const ushort* aB[4]; const ushort* bB[4];
  #pragma unroll
  for (int a = 0; a < 4; a++) {
    int rb = bx * 8 + wr * 4 + a;
    aB[a] = xb + (size_t)rb * 16 * 512 + lane * 8;
  }
  #pragma unroll
  for (int b = 0; b < 4; b++) {
    int cb = by * 8 + wc * 4 + b;
    bB[b] = yb + (size_t)cb * 16 * 512 + lane * 8;
  }

  f32x4 acc[4][4];
  #pragma unroll
  for (int a = 0; a < 4; a++)
    #pragma unroll
    for (int b = 0; b < 4; b++) acc[a][b] = (f32x4)(0.f);

  #pragma unroll
  for (int kb = 0; kb < NKB; ++kb) {
    bf16x8 af[4], bf[4];
    #pragma unroll
    for (int a = 0; a < 4; a++) af[a] = *(const bf16x8*)(aB[a] + kb * 512);
    #pragma unroll
    for (int b = 0; b < 4; b++) bf[b] = *(const bf16x8*)(bB[b] + kb * 512);
    #pragma unroll
    for (int a = 0; a < 4; a++)
      #pragma unroll
      for (int b = 0; b < 4; b++)
        acc[a][b] = __builtin_amdgcn_mfma_f32_16x16x32_bf16(af[a], bf[b], acc[a][b], 0, 0, 0);
  }

  // ---- fused epilogue (R6-proven) ----
  const float cut_c = fminf(fmaxf(cutoff[0], 0.f), 1000.f);
  const float q  = phi[0] * 1.4426950408889634f;   // phi * log2(e)
  const float qc = q * cut_c;
  const int rowBase = bx * BM + wr * 64;
  const int colBase = by * BN + wc * 64;

  float sq_j[4], sy_j[4];
  #pragma unroll
  for (int b = 0; b < 4; b++) {
    int j = colBase + b * 16 + l15;
    sq_j[b] = sqy[j];
    sy_j[b] = ssy[j];
  }
  #pragma unroll
  for (int a = 0; a < 4; a++) {
    float sq_i[4], sx_i[4];
    #pragma unroll
    for (int r = 0; r < 4; r++) {
      int i = rowBase + a * 16 + l16 * 4 + r;
      sq_i[r] = sqx[i];
      sx_i[r] = ssx[i];
    }
    #pragma unroll
    for (int b = 0; b < 4; b++) {
      #pragma unroll
      for (int r = 0; r < 4; r++) {
        int i = rowBase + a * 16 + l16 * 4 + r;
        int j = colBase + b * 16 + l15;
        float dot = acc[a][b][r];
        float d = __builtin_fmaf(-2.f, dot, sq_i[r] + sq_j[b]);
        float s = sx_i[r] * sy_j[b];
        float res = s * __builtin_amdgcn_rcpf(s + d);     // 1/(1+d/s)
        float earg = __builtin_fmaf(-q, res, qc);         // -phi*(res-cut)*log2e
        float u = __builtin_amdgcn_exp2f(earg);
        float o = res * __builtin_amdgcn_rcpf(1.f + u);   // res * sigmoid
        out[(size_t)i * M_ROWS + j] = o;
      }
    }
  }
}

extern "C" void kernel_launch(void* const* d_in, const int* in_sizes, int n_in,
                              void* d_out, int out_size, void* d_ws, size_t ws_size,
                              hipStream_t stream) {
  const float* x       = (const float*)d_in[0];
  const float* y       = (const float*)d_in[1];
  const float* samp_x  = (const float*)d_in[2];
  const float* samp_y  = (const float*)d_in[3];
  const float* scale   = (const float*)d_in[4];
  const float* cutoff  = (const float*)d_in[5];
  const float* phi     = (const float*)d_in[6];
  float* out = (float*)d_out;

  char* p = (char*)d_ws;
  ushort* xb = (ushort*)p; p += (size_t)N_ROWS * DDIM * 2;
  ushort* yb = (ushort*)p; p += (size_t)M_ROWS * DDIM * 2;
  float* sqx = (float*)p;  p += (size_t)N_ROWS * 4;
  float* sqy = (float*)p;  p += (size_t)M_ROWS * 4;
  float* ssx = (float*)p;  p += (size_t)N_ROWS * 4;
  float* ssy = (float*)p;  p += (size_t)M_ROWS * 4;

  prep_kernel<<<(N_ROWS + M_ROWS) / 4, 256, 0, stream>>>(
      x, y, samp_x, samp_y, scale, xb, yb, sqx, sqy, ssx, ssy);

  cauchy_gemm<<<(N_ROWS / BM) * (M_ROWS / BN), 256, 0, stream>>>(
      xb, yb, sqx, sqy, ssx, ssy, cutoff, phi, out);
}

// Round 14
// 58.017 us; speedup vs baseline: 1.4312x; 1.4312x over previous
//
#include <hip/hip_runtime.h>
#include <hip/hip_bf16.h>
#include <math.h>

#define N_ROWS 8192
#define M_ROWS 4096
#define DDIM   512
#define SDIM   16

#define BM 128
#define BN 128
#define BK 64

typedef __attribute__((ext_vector_type(8))) __bf16 bf16x8;
typedef __attribute__((ext_vector_type(4))) float f32x4;

__device__ __forceinline__ unsigned short f2bf_rne(float f) {
  unsigned u = __float_as_uint(f);
  u += 0x7fffu + ((u >> 16) & 1u);
  return (unsigned short)(u >> 16);
}

__device__ __forceinline__ void load_lds16(const void* g, void* l) {
  __builtin_amdgcn_global_load_lds(
      (const __attribute__((address_space(1))) void*)g,
      (__attribute__((address_space(3))) void*)l, 16, 0, 0);
}

// One row per WAVE (4 rows per 256-thread block) — R8-proven.
__global__ __launch_bounds__(256) void prep_kernel(
    const float* __restrict__ x, const float* __restrict__ y,
    const float* __restrict__ samp_x, const float* __restrict__ samp_y,
    const float* __restrict__ scale,
    ushort* __restrict__ xb, ushort* __restrict__ yb,
    float* __restrict__ sqx, float* __restrict__ sqy,
    float* __restrict__ ssx, float* __restrict__ ssy)
{
  const int tid  = threadIdx.x;
  const int lane = tid & 63;
  const int row  = blockIdx.x * 4 + (tid >> 6);

  const float* src; const float* samp; ushort* dst; float* sqo; float* sso;
  if (row < N_ROWS) {
    src = x + (size_t)row * DDIM; samp = samp_x + (size_t)row * SDIM;
    dst = xb + (size_t)row * DDIM; sqo = sqx + row; sso = ssx + row;
  } else {
    int r = row - N_ROWS;
    src = y + (size_t)r * DDIM; samp = samp_y + (size_t)r * SDIM;
    dst = yb + (size_t)r * DDIM; sqo = sqy + r; sso = ssy + r;
  }

  const float4 v0 = ((const float4*)src)[lane * 2];
  const float4 v1 = ((const float4*)src)[lane * 2 + 1];
  uint4 pk;
  pk.x = (unsigned)f2bf_rne(v0.x) | ((unsigned)f2bf_rne(v0.y) << 16);
  pk.y = (unsigned)f2bf_rne(v0.z) | ((unsigned)f2bf_rne(v0.w) << 16);
  pk.z = (unsigned)f2bf_rne(v1.x) | ((unsigned)f2bf_rne(v1.y) << 16);
  pk.w = (unsigned)f2bf_rne(v1.z) | ((unsigned)f2bf_rne(v1.w) << 16);
  ((uint4*)dst)[lane] = pk;

  float ss = v0.x * v0.x + v0.y * v0.y + v0.z * v0.z + v0.w * v0.w
           + v1.x * v1.x + v1.y * v1.y + v1.z * v1.z + v1.w * v1.w;
  #pragma unroll
  for (int m = 32; m >= 1; m >>= 1) ss += __shfl_xor(ss, m, 64);

  float p = (lane < SDIM) ? samp[lane] * scale[lane] : 0.f;
  #pragma unroll
  for (int m = 8; m >= 1; m >>= 1) p += __shfl_xor(p, m, 64);

  if (lane == 0) {
    *sqo = ss;
    float sp = (p > 15.f) ? p : log1pf(expf(p));   // softplus
    sp = fminf(fmaxf(sp, 1e-10f), 10000.f);
    *sso = sqrtf(sp);
  }
}

// R6-proven GEMM (byte-identical): 128x128 tile, BK=64, 4 waves (2x2 of
// 64x64 quads), SINGLE-buffered 32 KiB LDS, two __syncthreads per tile
// (vmcnt drain inside), TLP hides the drains; phase-separated DS pipe.
// XOR swizzle g^(row&7) on BOTH global source and ds_read (rule #21).
// Chunked XCD swizzle: XCD k owns bx in [8k,8k+8) for all by.
__global__ __launch_bounds__(256, 2) void cauchy_gemm(
    const ushort* __restrict__ xb, const ushort* __restrict__ yb,
    const float* __restrict__ sqx, const float* __restrict__ sqy,
    const float* __restrict__ ssx, const float* __restrict__ ssy,
    const float* __restrict__ cutoff, const float* __restrict__ phi,
    float* __restrict__ out)
{
  __shared__ ushort As[BM * BK];
  __shared__ ushort Bs[BN * BK];
  const int tid = threadIdx.x;
  const int lane = tid & 63;
  const int w = tid >> 6;
  const int wr = w >> 1, wc = w & 1;
  const int l15 = lane & 15, l16 = lane >> 4;

  const int bid   = blockIdx.x;
  const int xcd   = bid & 7;
  const int local = bid >> 3;
  const int wk    = local & 31;
  const int bx = xcd * 8 + (wk & 7);           // 64 row-blocks; bx in [8k,8k+8)
  const int by = (local >> 5) * 4 + (wk >> 3); // 32 col-blocks

  const size_t aBase = (size_t)bx * BM * DDIM;
  const size_t bBase = (size_t)by * BN * DDIM;

  f32x4 acc[4][4];
  #pragma unroll
  for (int a = 0; a < 4; a++)
    #pragma unroll
    for (int b = 0; b < 4; b++)
      acc[a][b] = (f32x4)(0.f);

  for (int k0 = 0; k0 < DDIM; k0 += BK) {
    #pragma unroll
    for (int c = 0; c < 4; c++) {
      int idx = c * 256 + tid;           // granule index in tile
      int row = idx >> 3;                // 8 granules (64 bf16) per row
      int g = idx & 7;
      int sg = g ^ (row & 7);            // pre-swizzle the SOURCE granule
      load_lds16(xb + aBase + (size_t)row * DDIM + k0 + sg * 8, As + idx * 8);
      load_lds16(yb + bBase + (size_t)row * DDIM + k0 + sg * 8, Bs + idx * 8);
    }
    __syncthreads();  // vmcnt(0) drain + barrier

    #pragma unroll
    for (int kk = 0; kk < 2; kk++) {
      bf16x8 af[4], bfr[4];
      #pragma unroll
      for (int a = 0; a < 4; a++) {
        int row = wr * 64 + a * 16 + l15;
        int gran = kk * 4 + l16;
        int off = row * BK + ((gran ^ (row & 7)) << 3);  // elements
        af[a] = *(const bf16x8*)((const char*)As + (size_t)off * 2);
      }
      #pragma unroll
      for (int b = 0; b < 4; b++) {
        int col = wc * 64 + b * 16 + l15;
        int gran = kk * 4 + l16;
        int off = col * BK + ((gran ^ (col & 7)) << 3);
        bfr[b] = *(const bf16x8*)((const char*)Bs + (size_t)off * 2);
      }
      #pragma unroll
      for (int a = 0; a < 4; a++)
        #pragma unroll
        for (int b = 0; b < 4; b++)
          acc[a][b] = __builtin_amdgcn_mfma_f32_16x16x32_bf16(af[a], bfr[b], acc[a][b], 0, 0, 0);
    }
    __syncthreads();
  }

  // ---- fused epilogue ----
  const float cut_c = fminf(fmaxf(cutoff[0], 0.f), 1000.f);
  const float q  = phi[0] * 1.4426950408889634f;   // phi * log2(e)
  const float qc = q * cut_c;
  const int rowBase = bx * BM + wr * 64;
  const int colBase = by * BN + wc * 64;

  float sq_j[4], sy_j[4];
  #pragma unroll
  for (int b = 0; b < 4; b++) {
    int j = colBase + b * 16 + l15;
    sq_j[b] = sqy[j];
    sy_j[b] = ssy[j];
  }
  #pragma unroll
  for (int a = 0; a < 4; a++) {
    float sq_i[4], sx_i[4];
    #pragma unroll
    for (int r = 0; r < 4; r++) {
      int i = rowBase + a * 16 + l16 * 4 + r;
      sq_i[r] = sqx[i];
      sx_i[r] = ssx[i];
    }
    #pragma unroll
    for (int b = 0; b < 4; b++) {
      #pragma unroll
      for (int r = 0; r < 4; r++) {
        int i = rowBase + a * 16 + l16 * 4 + r;
        int j = colBase + b * 16 + l15;
        float dot = acc[a][b][r];
        float d = __builtin_fmaf(-2.f, dot, sq_i[r] + sq_j[b]);
        float s = sx_i[r] * sy_j[b];
        float res = s * __builtin_amdgcn_rcpf(s + d);     // 1/(1+d/s)
        float earg = __builtin_fmaf(-q, res, qc);         // -phi*(res-cut)*log2e
        float u = __builtin_amdgcn_exp2f(earg);
        float o = res * __builtin_amdgcn_rcpf(1.f + u);   // res * sigmoid
        out[(size_t)i * M_ROWS + j] = o;
      }
    }
  }
}

extern "C" void kernel_launch(void* const* d_in, const int* in_sizes, int n_in,
                              void* d_out, int out_size, void* d_ws, size_t ws_size,
                              hipStream_t stream) {
  const float* x       = (const float*)d_in[0];
  const float* y       = (const float*)d_in[1];
  const float* samp_x  = (const float*)d_in[2];
  const float* samp_y  = (const float*)d_in[3];
  const float* scale   = (const float*)d_in[4];
  const float* cutoff  = (const float*)d_in[5];
  const float* phi     = (const float*)d_in[6];
  float* out = (float*)d_out;

  char* p = (char*)d_ws;
  ushort* xb = (ushort*)p; p += (size_t)N_ROWS * DDIM * 2;
  ushort* yb = (ushort*)p; p += (size_t)M_ROWS * DDIM * 2;
  float* sqx = (float*)p;  p += (size_t)N_ROWS * 4;
  float* sqy = (float*)p;  p += (size_t)M_ROWS * 4;
  float* ssx = (float*)p;  p += (size_t)N_ROWS * 4;
  float* ssy = (float*)p;  p += (size_t)M_ROWS * 4;

  prep_kernel<<<(N_ROWS + M_ROWS) / 4, 256, 0, stream>>>(
      x, y, samp_x, samp_y, scale, xb, yb, sqx, sqy, ssx, ssy);

  cauchy_gemm<<<(N_ROWS / BM) * (M_ROWS / BN), 256, 0, stream>>>(
      xb, yb, sqx, sqy, ssx, ssy, cutoff, phi, out);
}